// Round 11
// baseline (880.494 us; speedup 1.0000x reference)
//
#include <hip/hip_runtime.h>

#define NB 64
#define HW 4096           // 64*64

// ---------------------------------------------------------------------------
// K1: perceive (fixed stencil) + pre_life + zero accumulators.
// Block 1024: transpose W2 [48,128] -> W2T [128,48] (merged former k_prep).
// ---------------------------------------------------------------------------
__global__ __launch_bounds__(256) void k_perceive(
    const float* __restrict__ x, float* __restrict__ y_chw,
    float* __restrict__ y0_hwc, float* __restrict__ prelife,
    float* __restrict__ att_zero, const float* __restrict__ W2,
    float* __restrict__ W2T) {
  int t = threadIdx.x;
  if (blockIdx.x == 1024) {               // former k_prep
    for (int i = t; i < 6144; i += 256) {
      int o = i / 48;
      int c = i - o * 48;
      W2T[i] = W2[c * 128 + o];
    }
    return;
  }
  if (blockIdx.x == 0) {
    for (int i = t; i < 649; i += 256) att_zero[i] = 0.f;   // att_acc + ssq
  }
  int pix = blockIdx.x * 256 + t;
  int b = pix >> 12;
  int hw = pix & 4095;
  int h = hw >> 6, w = hw & 63;
  const float* xp = x + (size_t)pix * 8;
  bool hm = h > 0, hp = h < 63, wm = w > 0, wp = w < 63;

  float mx = -1e30f;
  #pragma unroll
  for (int di = -1; di <= 1; ++di) {
    if ((unsigned)(h + di) > 63u) continue;
    #pragma unroll
    for (int dj = -1; dj <= 1; ++dj) {
      if ((unsigned)(w + dj) > 63u) continue;
      mx = fmaxf(mx, xp[(di * 64 + dj) * 8 + 3]);
    }
  }
  prelife[pix] = (mx > 0.1f) ? 1.f : 0.f;

  float* yb = y_chw + (size_t)b * 16 * HW + hw;
  bool b0 = (b == 0);
  #pragma unroll
  for (int c = 0; c < 8; ++c) {
    float ctr = xp[c];
    float a00 = (hm && wm) ? xp[(-65) * 8 + c] : 0.f;
    float a02 = (hm && wp) ? xp[(-63) * 8 + c] : 0.f;
    float a20 = (hp && wm) ? xp[(63) * 8 + c] : 0.f;
    float a22 = (hp && wp) ? xp[(65) * 8 + c] : 0.f;
    float d = (a00 + a02 + a20 + a22) * 0.125f;   // dxk == dyk (symmetric)
    yb[(size_t)(c * 2 + 0) * HW] = ctr;
    yb[(size_t)(c * 2 + 1) * HW] = d;
    if (b0) {
      float* y0p = y0_hwc + hw * 24 + c * 3;
      y0p[0] = ctr; y0p[1] = d; y0p[2] = d;
    }
  }
}

// ---------------------------------------------------------------------------
// K2: attention mat-vec, batch 0 only (reads 255 MB of W_att -> HBM-bound).
// ---------------------------------------------------------------------------
__global__ __launch_bounds__(256) void k_att(
    const float* __restrict__ y0, const float* __restrict__ Watt,
    float* __restrict__ att_acc) {
  int t = threadIdx.x;
  int r0 = blockIdx.x * 128;
  float a0 = 0.f, a1 = 0.f, a2 = 0.f;
  for (int r = 0; r < 128; ++r) {
    float yv = y0[r0 + r];
    const float* wr = Watt + (size_t)(r0 + r) * 648;
    a0 = fmaf(yv, wr[t], a0);
    a1 = fmaf(yv, wr[t + 256], a1);
    if (t < 136) a2 = fmaf(yv, wr[t + 512], a2);
  }
  atomicAdd(att_acc + t, a0);
  atomicAdd(att_acc + t + 256, a1);
  if (t < 136) atomicAdd(att_acc + t + 512, a2);
}

// ---------------------------------------------------------------------------
// K3: blocks 0..1023: ssq = ||y2||^2 without materializing y2.
//     blocks 1024..1048: fold dw2 o conv1 -> K16 (3 outs/thr).
// ---------------------------------------------------------------------------
__global__ __launch_bounds__(256) void k_ssqfold(
    const float* __restrict__ y_chw, const float* __restrict__ att_acc,
    const float* __restrict__ b_att, float* __restrict__ ssq,
    const float* __restrict__ W1, float* __restrict__ K16) {
  __shared__ float ys[648];
  __shared__ float s[16 * 324];
  int t = threadIdx.x;

  if (blockIdx.x >= 1024) {               // fold path
    for (int i = t; i < 648; i += 256) ys[i] = att_acc[i] + b_att[i];
    __syncthreads();
    int r = blockIdx.x - 1024;            // 0..24
    int ri = r / 5, rj = r - ri * 5;
    #pragma unroll
    for (int k = 0; k < 3; ++k) {
      int idx = t + 256 * k;              // 0..767
      int p = idx / 48;                   // 0..15
      int o = idx - p * 48;               // 0..47
      int c = p >> 1, tt = p & 1;
      float acc = 0.f;
      for (int ki = 0; ki < 3; ++ki) {
        int qi = ri - ki;
        if ((unsigned)qi > 2u) continue;
        for (int kj = 0; kj < 3; ++kj) {
          int qj = rj - kj;
          if ((unsigned)qj > 2u) continue;
          int k9 = ki * 3 + kj, q9 = qi * 3 + qj;
          const float* wb = W1 + (size_t)(k9 * 72 + 9 * c) * 48 + o;
          const float* yb = ys + q9 * 72 + 9 * c;
          if (tt == 0) {
            #pragma unroll
            for (int m = 0; m < 3; ++m) acc = fmaf(wb[(size_t)m * 48], yb[m], acc);
          } else {
            #pragma unroll
            for (int m = 0; m < 3; ++m) {
              acc = fmaf(wb[(size_t)(3 + m) * 48], yb[3 + m], acc);
              acc = fmaf(wb[(size_t)(6 + m) * 48], yb[6 + m], acc);
            }
          }
        }
      }
      K16[(size_t)(r * 16 + p) * 48 + o] = acc;
    }
    return;
  }

  for (int i = t; i < 648; i += 256) ys[i] = att_acc[i] + b_att[i];

  int blk = blockIdx.x;
  int b = blk >> 4;
  int tile = blk & 15;
  int i0 = (tile >> 2) * 16;
  int j0 = (tile & 3) * 16;
  const float* yb = y_chw + (size_t)b * 16 * HW;

  for (int idx = t; idx < 16 * 324; idx += 256) {
    int c = idx / 324;
    int pos = idx - c * 324;
    int r = pos / 18, col = pos - r * 18;
    int gr = i0 - 1 + r, gc = j0 - 1 + col;
    bool v = ((unsigned)gr < 64u) && ((unsigned)gc < 64u);
    s[idx] = v ? yb[(size_t)c * HW + gr * 64 + gc] : 0.f;
  }
  __syncthreads();

  int ty = t >> 4, tx = t & 15;
  float local = 0.f;
  for (int c = 0; c < 8; ++c) {
    float tapA[9], tapB[9];
    const float* sa = s + (size_t)(2 * c) * 324 + ty * 18 + tx;
    const float* sb = s + (size_t)(2 * c + 1) * 324 + ty * 18 + tx;
    #pragma unroll
    for (int di = 0; di < 3; ++di)
      #pragma unroll
      for (int dj = 0; dj < 3; ++dj) {
        tapA[di * 3 + dj] = sa[di * 18 + dj];
        tapB[di * 3 + dj] = sb[di * 18 + dj];
      }
    #pragma unroll
    for (int m = 0; m < 3; ++m) {
      float z0 = 0.f, z1 = 0.f, z2 = 0.f;
      #pragma unroll
      for (int k9 = 0; k9 < 9; ++k9) {
        z0 = fmaf(tapA[k9], ys[k9 * 72 + 9 * c + m], z0);
        z1 = fmaf(tapB[k9], ys[k9 * 72 + 9 * c + 3 + m], z1);
        z2 = fmaf(tapB[k9], ys[k9 * 72 + 9 * c + 6 + m], z2);
      }
      local += z0 * z0 + z1 * z1 + z2 * z2;
    }
  }
  #pragma unroll
  for (int off = 32; off; off >>= 1) local += __shfl_down(local, off, 64);
  if ((t & 63) == 0) atomicAdd(ssq, local);
}

// ---------------------------------------------------------------------------
// K4: folded conv1 (5x5 on 16 planes -> 48). R10 post-mortem: occupancy was
// GRID-capped (1024 blocks = 4 blocks/CU = 50%). Now grid 2048: tile 8x16,
// og-split, P=1 (acc[24], 1 px/thread). Staging 8 planes x 12x20 x 2 phases
// (7.7KB). FMA order per output unchanged -> bit-identical results.
// Overlap tiles (i0 54, j0 46 clamps) rewrite identical values: benign.
// ---------------------------------------------------------------------------
__global__ __launch_bounds__(256, 8) void k_conv1f(
    const float* __restrict__ y_chw, const float* __restrict__ K16,
    const float* __restrict__ b1, const float* __restrict__ ssqp,
    float* __restrict__ h1) {
  __shared__ float s[8 * 240];
  int t = threadIdx.x;
  int og = __builtin_amdgcn_readfirstlane(t >> 7);      // wave-uniform 0/1
  int sub = t & 127;
  int ty = sub >> 4, tx = sub & 15;                     // ty 0..7
  int blk = blockIdx.x;
  int b = blk >> 5;
  int tile = blk & 31;
  int i0 = (tile >> 2) * 8;  if (i0 > 54) i0 = 54;
  int j0 = (tile & 3) * 16;  if (j0 > 46) j0 = 46;

  const float* yb = y_chw + (size_t)b * 16 * HW;
  float acc[24];
  #pragma unroll
  for (int o = 0; o < 24; ++o) acc[o] = 0.f;

  for (int c0 = 0; c0 < 16; c0 += 8) {
    __syncthreads();
    for (int idx = t; idx < 8 * 240; idx += 256) {
      int c = idx / 240;
      int pos = idx - c * 240;
      int r = pos / 20, col = pos - r * 20;
      int gr = i0 - 1 + r, gc = j0 - 1 + col;
      bool v = ((unsigned)gr < 64u) && ((unsigned)gc < 64u);
      s[idx] = v ? yb[(size_t)(c0 + c) * HW + gr * 64 + gc] : 0.f;
    }
    __syncthreads();
    for (int c = 0; c < 8; ++c) {
      const float* sc = s + c * 240 + ty * 20 + tx;
      #pragma unroll
      for (int ri = 0; ri < 5; ++ri) {
        float t0[5];
        #pragma unroll
        for (int rj = 0; rj < 5; ++rj) t0[rj] = sc[ri * 20 + rj];
        #pragma unroll
        for (int rj = 0; rj < 5; ++rj) {
          const float* w = K16 + (size_t)((ri * 5 + rj) * 16 + c0 + c) * 48 + og * 24;  // SGPR
          float tv = t0[rj];
          #pragma unroll
          for (int o = 0; o < 24; ++o) acc[o] = fmaf(tv, w[o], acc[o]);
        }
      }
    }
  }
  float inv = rsqrtf(fmaxf(ssqp[0], 1e-12f));
  float* hb = h1 + (size_t)b * 48 * 3844 + (size_t)og * 24 * 3844
            + (i0 + ty) * 62 + (j0 + tx);
  #pragma unroll
  for (int o = 0; o < 24; ++o)
    hb[(size_t)o * 3844] = fmaf(acc[o], inv, b1[og * 24 + o]);
}

// ---------------------------------------------------------------------------
// K5: fused convT (3x3 pad-2, 48->48) + head (48->128 relu ->8) + residual.
// R10 post-mortem: grid-capped occupancy. Now grid 2048: tile 8x16 (64
// divisible: no clamps), og-split conv P=1. Staging 24ch x 10x18 x 2 phases
// (17.3KB -> 9 blocks/CU by LDS; grid allows 8). Exchange: 2 x 24-ch phases.
// Head O-SPLIT: og-half g does o in [64g,64g+64) for its pixel; og1 partial
// dx combined via stride-9 LDS region (no bank conflict). dx sum order
// changes (split sum) -> absmax may move in last bits only.
// ---------------------------------------------------------------------------
__global__ __launch_bounds__(256, 6) void k_convTh(
    const float* __restrict__ h1, const float* __restrict__ Wt,
    const float* __restrict__ bt, const float* __restrict__ W2T,
    const float* __restrict__ b2, const float* __restrict__ W3,
    const float* __restrict__ b3, const float* __restrict__ x,
    const float* __restrict__ noise, float* __restrict__ x2,
    float* __restrict__ alpha2) {
  __shared__ float s[24 * 180];           // 4320 fl; exchange uses 24*128=3072
  int t = threadIdx.x;
  int og = __builtin_amdgcn_readfirstlane(t >> 7);      // wave-uniform 0/1
  int sub = t & 127;
  int ty = sub >> 4, tx = sub & 15;                     // ty 0..7
  int blk = blockIdx.x;
  int b = blk >> 5;
  int tile = blk & 31;
  int i0 = (tile >> 2) * 8;               // 0..56
  int j0 = (tile & 3) * 16;               // 0..48

  float acc[24];
  #pragma unroll
  for (int o = 0; o < 24; ++o) acc[o] = 0.f;
  const float* hb = h1 + (size_t)b * 48 * 3844;

  for (int c0 = 0; c0 < 48; c0 += 24) {
    __syncthreads();
    for (int idx = t; idx < 24 * 180; idx += 256) {
      int c = idx / 180;
      int pos = idx - c * 180;
      int r = pos / 18, col = pos - r * 18;
      int gr = i0 - 2 + r, gc = j0 - 2 + col;
      bool v = ((unsigned)gr < 62u) && ((unsigned)gc < 62u);
      s[idx] = v ? hb[(size_t)(c0 + c) * 3844 + gr * 62 + gc] : 0.f;
    }
    __syncthreads();
    for (int c = 0; c < 24; ++c) {
      const float* sc = s + c * 180 + ty * 18 + tx;
      float tap[9];
      #pragma unroll
      for (int di = 0; di < 3; ++di)
        #pragma unroll
        for (int dj = 0; dj < 3; ++dj) tap[di * 3 + dj] = sc[di * 18 + dj];
      #pragma unroll
      for (int k9 = 0; k9 < 9; ++k9) {
        const float* w = Wt + (size_t)(k9 * 48 + c0 + c) * 48 + og * 24;  // SGPR
        float tv = tap[k9];
        #pragma unroll
        for (int o = 0; o < 24; ++o) acc[o] = fmaf(tv, w[o], acc[o]);
      }
    }
  }

  // two-phase h2 exchange (24 ch x 128 px each), reads stride-1: no conflict
  float hr[48];
  __syncthreads();
  if (og == 0) {
    #pragma unroll
    for (int o = 0; o < 24; ++o) s[o * 128 + sub] = acc[o] + bt[o];
  }
  __syncthreads();
  #pragma unroll
  for (int c = 0; c < 24; ++c) hr[c] = s[c * 128 + sub];
  __syncthreads();
  if (og == 1) {
    #pragma unroll
    for (int o = 0; o < 24; ++o) s[o * 128 + sub] = acc[o] + bt[24 + o];
  }
  __syncthreads();
  #pragma unroll
  for (int c = 0; c < 24; ++c) hr[24 + c] = s[c * 128 + sub];

  // head, o-split: this half does o in [og*64, og*64+64)
  int pix = b * 4096 + (i0 + ty) * 64 + (j0 + tx);
  float dx[8];
  #pragma unroll
  for (int k = 0; k < 8; ++k) dx[k] = og ? 0.f : b3[k];
  #pragma unroll 4
  for (int oo = 0; oo < 64; ++oo) {
    int o = og * 64 + oo;                 // wave-uniform
    float v = b2[o];
    const float* w2 = W2T + o * 48;       // contiguous row -> s_load
    #pragma unroll
    for (int c = 0; c < 48; ++c) v = fmaf(hr[c], w2[c], v);
    v = fmaxf(v, 0.f);
    const float* w3 = W3 + o * 8;
    #pragma unroll
    for (int k = 0; k < 8; ++k) dx[k] = fmaf(v, w3[k], dx[k]);
  }
  // combine og1 partials into og0 (stride-9 pad: banks spread)
  __syncthreads();
  if (og == 1) {
    #pragma unroll
    for (int k = 0; k < 8; ++k) s[sub * 9 + k] = dx[k];
  }
  __syncthreads();
  if (og == 0) {
    #pragma unroll
    for (int k = 0; k < 8; ++k) dx[k] += s[sub * 9 + k];
    float m = (noise[pix] <= 0.5f) ? 1.f : 0.f;
    const float* xp = x + (size_t)pix * 8;
    float* xo = x2 + (size_t)pix * 8;
    float a3 = 0.f;
    #pragma unroll
    for (int k = 0; k < 8; ++k) {
      float v = fmaf(dx[k], m, xp[k]);
      xo[k] = v;
      if (k == 3) a3 = v;
    }
    alpha2[pix] = a3;
  }
}

// ---------------------------------------------------------------------------
// K7: post_life maxpool + alive gating -> d_out
// ---------------------------------------------------------------------------
__global__ __launch_bounds__(256) void k_life(
    const float* __restrict__ x2, const float* __restrict__ alpha2,
    const float* __restrict__ prelife, float* __restrict__ out) {
  int pix = blockIdx.x * 256 + threadIdx.x;
  int hw = pix & 4095;
  int h = hw >> 6, w = hw & 63;
  const float* ab = alpha2 + (size_t)(pix - hw);
  float mx = -1e30f;
  #pragma unroll
  for (int di = -1; di <= 1; ++di) {
    if ((unsigned)(h + di) > 63u) continue;
    #pragma unroll
    for (int dj = -1; dj <= 1; ++dj) {
      if ((unsigned)(w + dj) > 63u) continue;
      mx = fmaxf(mx, ab[(h + di) * 64 + (w + dj)]);
    }
  }
  float life = (mx > 0.1f && prelife[pix] > 0.5f) ? 1.f : 0.f;
  const float* xp = x2 + (size_t)pix * 8;
  float* op = out + (size_t)pix * 8;
  #pragma unroll
  for (int k = 0; k < 8; ++k) op[k] = xp[k] * life;
}

// ---------------------------------------------------------------------------
extern "C" void kernel_launch(void* const* d_in, const int* in_sizes, int n_in,
                              void* d_out, int out_size, void* d_ws, size_t ws_size,
                              hipStream_t stream) {
  const float* x     = (const float*)d_in[0];
  const float* noise = (const float*)d_in[1];
  const float* Watt  = (const float*)d_in[2];
  const float* b_att = (const float*)d_in[3];
  const float* W1    = (const float*)d_in[4];
  const float* b1    = (const float*)d_in[5];
  const float* Wt    = (const float*)d_in[6];
  const float* bt    = (const float*)d_in[7];
  const float* W2    = (const float*)d_in[8];
  const float* b2    = (const float*)d_in[9];
  const float* W3    = (const float*)d_in[10];
  const float* b3    = (const float*)d_in[11];
  float* out = (float*)d_out;

  float* ws = (float*)d_ws;
  size_t o_y   = 0;                       // y16 [4194304]; later x2+alpha2
  size_t o_h1  = o_y + 4194304;           // h1 [11808768]
  size_t o_y0  = o_h1 + 11808768;         // y0_hwc [98304]
  size_t o_pre = o_y0 + 98304;            // prelife [262144]
  size_t o_att = o_pre + 262144;          // att_acc[648] + ssq[1]
  size_t o_w2t = o_att + 652;             // W2T [6144]
  size_t o_k16 = o_w2t + 6144;            // K16 [19200]
  float* y_chw   = ws + o_y;
  float* h1_chw  = ws + o_h1;
  float* y0_hwc  = ws + o_y0;
  float* prelife = ws + o_pre;
  float* att_acc = ws + o_att;
  float* ssq     = ws + o_att + 648;
  float* W2T     = ws + o_w2t;
  float* K16     = ws + o_k16;
  float* x2      = ws + o_y;              // alias: y dead after k_conv1f
  float* alpha2  = ws + o_y + 2097152;

  k_perceive<<<1025, 256, 0, stream>>>(x, y_chw, y0_hwc, prelife, att_acc, W2, W2T);
  k_att<<<768, 256, 0, stream>>>(y0_hwc, Watt, att_acc);
  k_ssqfold<<<1049, 256, 0, stream>>>(y_chw, att_acc, b_att, ssq, W1, K16);
  k_conv1f<<<2048, 256, 0, stream>>>(y_chw, K16, b1, ssq, h1_chw);
  k_convTh<<<2048, 256, 0, stream>>>(h1_chw, Wt, bt, W2T, b2, W3, b3, x, noise, x2, alpha2);
  k_life<<<1024, 256, 0, stream>>>(x2, alpha2, prelife, out);
}

// Round 12
// 831.237 us; speedup vs baseline: 1.0593x; 1.0593x over previous
//
#include <hip/hip_runtime.h>

#define NB 64
#define HW 4096           // 64*64

// ---------------------------------------------------------------------------
// K1: perceive (fixed stencil) + pre_life + zero accumulators.
// Block 1024: transpose W2 [48,128] -> W2T [128,48] (merged former k_prep).
// ---------------------------------------------------------------------------
__global__ __launch_bounds__(256) void k_perceive(
    const float* __restrict__ x, float* __restrict__ y_chw,
    float* __restrict__ y0_hwc, float* __restrict__ prelife,
    float* __restrict__ att_zero, const float* __restrict__ W2,
    float* __restrict__ W2T) {
  int t = threadIdx.x;
  if (blockIdx.x == 1024) {               // former k_prep
    for (int i = t; i < 6144; i += 256) {
      int o = i / 48;
      int c = i - o * 48;
      W2T[i] = W2[c * 128 + o];
    }
    return;
  }
  if (blockIdx.x == 0) {
    for (int i = t; i < 649; i += 256) att_zero[i] = 0.f;   // att_acc + ssq
  }
  int pix = blockIdx.x * 256 + t;
  int b = pix >> 12;
  int hw = pix & 4095;
  int h = hw >> 6, w = hw & 63;
  const float* xp = x + (size_t)pix * 8;
  bool hm = h > 0, hp = h < 63, wm = w > 0, wp = w < 63;

  float mx = -1e30f;
  #pragma unroll
  for (int di = -1; di <= 1; ++di) {
    if ((unsigned)(h + di) > 63u) continue;
    #pragma unroll
    for (int dj = -1; dj <= 1; ++dj) {
      if ((unsigned)(w + dj) > 63u) continue;
      mx = fmaxf(mx, xp[(di * 64 + dj) * 8 + 3]);
    }
  }
  prelife[pix] = (mx > 0.1f) ? 1.f : 0.f;

  float* yb = y_chw + (size_t)b * 16 * HW + hw;
  bool b0 = (b == 0);
  #pragma unroll
  for (int c = 0; c < 8; ++c) {
    float ctr = xp[c];
    float a00 = (hm && wm) ? xp[(-65) * 8 + c] : 0.f;
    float a02 = (hm && wp) ? xp[(-63) * 8 + c] : 0.f;
    float a20 = (hp && wm) ? xp[(63) * 8 + c] : 0.f;
    float a22 = (hp && wp) ? xp[(65) * 8 + c] : 0.f;
    float d = (a00 + a02 + a20 + a22) * 0.125f;   // dxk == dyk (symmetric)
    yb[(size_t)(c * 2 + 0) * HW] = ctr;
    yb[(size_t)(c * 2 + 1) * HW] = d;
    if (b0) {
      float* y0p = y0_hwc + hw * 24 + c * 3;
      y0p[0] = ctr; y0p[1] = d; y0p[2] = d;
    }
  }
}

// ---------------------------------------------------------------------------
// K2: attention mat-vec, batch 0 only (reads 255 MB of W_att -> HBM-bound).
// R12: grid 768->1536 (64 rows/block) + 2-row software pipelining: 6
// independent load+FMA chains per iter for 2x memory-level parallelism.
// Old shape (3 blocks/CU, serial 128-iter loop) couldn't keep ~2.3MB of
// loads in flight -> suspected 2-4 TB/s effective, not ~6.
// ---------------------------------------------------------------------------
__global__ __launch_bounds__(256) void k_att(
    const float* __restrict__ y0, const float* __restrict__ Watt,
    float* __restrict__ att_acc) {
  int t = threadIdx.x;
  int r0 = blockIdx.x * 64;
  float a0 = 0.f, a1 = 0.f, a2 = 0.f;
  float b0 = 0.f, b1 = 0.f, b2 = 0.f;
  for (int r = 0; r < 64; r += 2) {
    float yv0 = y0[r0 + r];
    float yv1 = y0[r0 + r + 1];
    const float* w0 = Watt + (size_t)(r0 + r) * 648;
    const float* w1 = w0 + 648;
    a0 = fmaf(yv0, w0[t], a0);
    b0 = fmaf(yv1, w1[t], b0);
    a1 = fmaf(yv0, w0[t + 256], a1);
    b1 = fmaf(yv1, w1[t + 256], b1);
    if (t < 136) {
      a2 = fmaf(yv0, w0[t + 512], a2);
      b2 = fmaf(yv1, w1[t + 512], b2);
    }
  }
  atomicAdd(att_acc + t, a0 + b0);
  atomicAdd(att_acc + t + 256, a1 + b1);
  if (t < 136) atomicAdd(att_acc + t + 512, a2 + b2);
}

// ---------------------------------------------------------------------------
// K3: blocks 0..1023: ssq = ||y2||^2 without materializing y2.
//     blocks 1024..1048: fold dw2 o conv1 -> K16 (3 outs/thr).
// ---------------------------------------------------------------------------
__global__ __launch_bounds__(256) void k_ssqfold(
    const float* __restrict__ y_chw, const float* __restrict__ att_acc,
    const float* __restrict__ b_att, float* __restrict__ ssq,
    const float* __restrict__ W1, float* __restrict__ K16) {
  __shared__ float ys[648];
  __shared__ float s[16 * 324];
  int t = threadIdx.x;

  if (blockIdx.x >= 1024) {               // fold path
    for (int i = t; i < 648; i += 256) ys[i] = att_acc[i] + b_att[i];
    __syncthreads();
    int r = blockIdx.x - 1024;            // 0..24
    int ri = r / 5, rj = r - ri * 5;
    #pragma unroll
    for (int k = 0; k < 3; ++k) {
      int idx = t + 256 * k;              // 0..767
      int p = idx / 48;                   // 0..15
      int o = idx - p * 48;               // 0..47
      int c = p >> 1, tt = p & 1;
      float acc = 0.f;
      for (int ki = 0; ki < 3; ++ki) {
        int qi = ri - ki;
        if ((unsigned)qi > 2u) continue;
        for (int kj = 0; kj < 3; ++kj) {
          int qj = rj - kj;
          if ((unsigned)qj > 2u) continue;
          int k9 = ki * 3 + kj, q9 = qi * 3 + qj;
          const float* wb = W1 + (size_t)(k9 * 72 + 9 * c) * 48 + o;
          const float* yb = ys + q9 * 72 + 9 * c;
          if (tt == 0) {
            #pragma unroll
            for (int m = 0; m < 3; ++m) acc = fmaf(wb[(size_t)m * 48], yb[m], acc);
          } else {
            #pragma unroll
            for (int m = 0; m < 3; ++m) {
              acc = fmaf(wb[(size_t)(3 + m) * 48], yb[3 + m], acc);
              acc = fmaf(wb[(size_t)(6 + m) * 48], yb[6 + m], acc);
            }
          }
        }
      }
      K16[(size_t)(r * 16 + p) * 48 + o] = acc;
    }
    return;
  }

  for (int i = t; i < 648; i += 256) ys[i] = att_acc[i] + b_att[i];

  int blk = blockIdx.x;
  int b = blk >> 4;
  int tile = blk & 15;
  int i0 = (tile >> 2) * 16;
  int j0 = (tile & 3) * 16;
  const float* yb = y_chw + (size_t)b * 16 * HW;

  for (int idx = t; idx < 16 * 324; idx += 256) {
    int c = idx / 324;
    int pos = idx - c * 324;
    int r = pos / 18, col = pos - r * 18;
    int gr = i0 - 1 + r, gc = j0 - 1 + col;
    bool v = ((unsigned)gr < 64u) && ((unsigned)gc < 64u);
    s[idx] = v ? yb[(size_t)c * HW + gr * 64 + gc] : 0.f;
  }
  __syncthreads();

  int ty = t >> 4, tx = t & 15;
  float local = 0.f;
  for (int c = 0; c < 8; ++c) {
    float tapA[9], tapB[9];
    const float* sa = s + (size_t)(2 * c) * 324 + ty * 18 + tx;
    const float* sb = s + (size_t)(2 * c + 1) * 324 + ty * 18 + tx;
    #pragma unroll
    for (int di = 0; di < 3; ++di)
      #pragma unroll
      for (int dj = 0; dj < 3; ++dj) {
        tapA[di * 3 + dj] = sa[di * 18 + dj];
        tapB[di * 3 + dj] = sb[di * 18 + dj];
      }
    #pragma unroll
    for (int m = 0; m < 3; ++m) {
      float z0 = 0.f, z1 = 0.f, z2 = 0.f;
      #pragma unroll
      for (int k9 = 0; k9 < 9; ++k9) {
        z0 = fmaf(tapA[k9], ys[k9 * 72 + 9 * c + m], z0);
        z1 = fmaf(tapB[k9], ys[k9 * 72 + 9 * c + 3 + m], z1);
        z2 = fmaf(tapB[k9], ys[k9 * 72 + 9 * c + 6 + m], z2);
      }
      local += z0 * z0 + z1 * z1 + z2 * z2;
    }
  }
  #pragma unroll
  for (int off = 32; off; off >>= 1) local += __shfl_down(local, off, 64);
  if ((t & 63) == 0) atomicAdd(ssq, local);
}

// ---------------------------------------------------------------------------
// K4: folded conv1 = 5x5 VALID-on-padded, 16 distinct planes -> 48,
// LDS-tiled 16x16 (+2 halo), og-split + P=2 rows per thread. 19200 FMA/thr.
// (Exact R8-winner form: single 16-plane staging, grid 1024.)
// ---------------------------------------------------------------------------
__global__ __launch_bounds__(256, 4) void k_conv1f(
    const float* __restrict__ y_chw, const float* __restrict__ K16,
    const float* __restrict__ b1, const float* __restrict__ ssqp,
    float* __restrict__ h1) {
  __shared__ float s[16 * 400];
  int t = threadIdx.x;
  int og = __builtin_amdgcn_readfirstlane(t >> 7);      // wave-uniform 0/1
  int sub = t & 127;
  int ty = sub >> 4, tx = sub & 15;                     // ty 0..7
  int blk = blockIdx.x;
  int b = blk >> 4;
  int tile = blk & 15;
  int i0 = (tile >> 2) * 16; if (i0 > 46) i0 = 46;
  int j0 = (tile & 3) * 16;  if (j0 > 46) j0 = 46;

  const float* yb = y_chw + (size_t)b * 16 * HW;
  for (int idx = t; idx < 16 * 400; idx += 256) {
    int c = idx / 400;
    int pos = idx - c * 400;
    int r = pos / 20, col = pos - r * 20;
    int gr = i0 - 1 + r, gc = j0 - 1 + col;
    bool v = ((unsigned)gr < 64u) && ((unsigned)gc < 64u);
    s[idx] = v ? yb[(size_t)c * HW + gr * 64 + gc] : 0.f;
  }
  __syncthreads();

  float acc0[24], acc1[24];
  #pragma unroll
  for (int o = 0; o < 24; ++o) { acc0[o] = 0.f; acc1[o] = 0.f; }

  for (int c = 0; c < 16; ++c) {
    const float* sc = s + (size_t)c * 400 + ty * 20 + tx;
    #pragma unroll
    for (int ri = 0; ri < 5; ++ri) {
      float t0[5], t1[5];
      #pragma unroll
      for (int rj = 0; rj < 5; ++rj) {
        t0[rj] = sc[ri * 20 + rj];
        t1[rj] = sc[(ri + 8) * 20 + rj];
      }
      #pragma unroll
      for (int rj = 0; rj < 5; ++rj) {
        const float* w = K16 + (size_t)((ri * 5 + rj) * 16 + c) * 48 + og * 24;  // SGPR
        float tv0 = t0[rj], tv1 = t1[rj];
        #pragma unroll
        for (int o = 0; o < 24; ++o) {
          acc0[o] = fmaf(tv0, w[o], acc0[o]);
          acc1[o] = fmaf(tv1, w[o], acc1[o]);
        }
      }
    }
  }
  float inv = rsqrtf(fmaxf(ssqp[0], 1e-12f));
  float* hb = h1 + (size_t)b * 48 * 3844 + (size_t)og * 24 * 3844
            + (i0 + ty) * 62 + (j0 + tx);
  #pragma unroll
  for (int o = 0; o < 24; ++o) {
    float bo = b1[og * 24 + o];
    hb[(size_t)o * 3844] = fmaf(acc0[o], inv, bo);
    hb[(size_t)o * 3844 + 8 * 62] = fmaf(acc1[o], inv, bo);
  }
}

// ---------------------------------------------------------------------------
// K5: fused convT (3x3 pad-2 correlation 48->48) + head (48->128 relu ->8)
// + masked residual. Exact R8-winner form: 24-ch 2-phase staging (31KB LDS),
// two-phase 24-ch LDS exchange, head unroll-4, grid 1024, (256,4).
// Measured: 220us, VGPR 44, VALUBusy 67%, Occ 41% -- control for this round.
// ---------------------------------------------------------------------------
__global__ __launch_bounds__(256, 4) void k_convTh(
    const float* __restrict__ h1, const float* __restrict__ Wt,
    const float* __restrict__ bt, const float* __restrict__ W2T,
    const float* __restrict__ b2, const float* __restrict__ W3,
    const float* __restrict__ b3, const float* __restrict__ x,
    const float* __restrict__ noise, float* __restrict__ x2,
    float* __restrict__ alpha2) {
  __shared__ float s[24 * 324];           // staging 7776 fl; exchange uses 6144
  int t = threadIdx.x;
  int og = __builtin_amdgcn_readfirstlane(t >> 7);      // wave-uniform 0/1
  int sub = t & 127;
  int ty = sub >> 4, tx = sub & 15;
  int blk = blockIdx.x;
  int b = blk >> 4;
  int tile = blk & 15;
  int i0 = (tile >> 2) * 16;
  int j0 = (tile & 3) * 16;

  float acc0[24], acc1[24];
  #pragma unroll
  for (int o = 0; o < 24; ++o) { acc0[o] = 0.f; acc1[o] = 0.f; }
  const float* hb = h1 + (size_t)b * 48 * 3844;

  for (int c0 = 0; c0 < 48; c0 += 24) {
    __syncthreads();
    for (int idx = t; idx < 24 * 324; idx += 256) {
      int c = idx / 324;
      int pos = idx - c * 324;
      int r = pos / 18, col = pos - r * 18;
      int gr = i0 - 2 + r, gc = j0 - 2 + col;
      bool v = ((unsigned)gr < 62u) && ((unsigned)gc < 62u);
      s[idx] = v ? hb[(size_t)(c0 + c) * 3844 + gr * 62 + gc] : 0.f;
    }
    __syncthreads();
    for (int c = 0; c < 24; ++c) {
      const float* sc = s + c * 324 + ty * 18 + tx;
      float tap0[9], tap1[9];
      #pragma unroll
      for (int di = 0; di < 3; ++di)
        #pragma unroll
        for (int dj = 0; dj < 3; ++dj) {
          tap0[di * 3 + dj] = sc[di * 18 + dj];
          tap1[di * 3 + dj] = sc[(di + 8) * 18 + dj];
        }
      #pragma unroll
      for (int k9 = 0; k9 < 9; ++k9) {
        const float* w = Wt + (size_t)(k9 * 48 + c0 + c) * 48 + og * 24;  // SGPR
        float tv0 = tap0[k9], tv1 = tap1[k9];
        #pragma unroll
        for (int o = 0; o < 24; ++o) {
          acc0[o] = fmaf(tv0, w[o], acc0[o]);
          acc1[o] = fmaf(tv1, w[o], acc1[o]);
        }
      }
    }
  }

  // two-phase h2-tile exchange: og==ph writes its 24 channels (24x256 region
  // of s), then ALL threads read their pixel's 24 values. Static hr idx.
  float hr[48];
  #pragma unroll
  for (int ph = 0; ph < 2; ++ph) {
    __syncthreads();                      // prior reads of s done
    if (og == ph) {
      #pragma unroll
      for (int o = 0; o < 24; ++o) {
        float bo = bt[ph * 24 + o];
        s[o * 256 + ty * 16 + tx] = acc0[o] + bo;
        s[o * 256 + (ty + 8) * 16 + tx] = acc1[o] + bo;
      }
    }
    __syncthreads();
    #pragma unroll
    for (int c = 0; c < 24; ++c) hr[ph * 24 + c] = s[c * 256 + t];  // stride-1: conflict-free
  }

  // head: one pixel per thread; unroll 4 -> 4 independent dep-chains
  int pty = t >> 4, ptx = t & 15;
  int pix = b * 4096 + (i0 + pty) * 64 + (j0 + ptx);
  float dx[8];
  #pragma unroll
  for (int k = 0; k < 8; ++k) dx[k] = b3[k];
  #pragma unroll 4
  for (int o = 0; o < 128; ++o) {
    float v = b2[o];
    const float* w2 = W2T + o * 48;       // contiguous row -> s_load
    #pragma unroll
    for (int c = 0; c < 48; ++c) v = fmaf(hr[c], w2[c], v);
    v = fmaxf(v, 0.f);
    const float* w3 = W3 + o * 8;
    #pragma unroll
    for (int k = 0; k < 8; ++k) dx[k] = fmaf(v, w3[k], dx[k]);
  }
  float m = (noise[pix] <= 0.5f) ? 1.f : 0.f;
  const float* xp = x + (size_t)pix * 8;
  float* xo = x2 + (size_t)pix * 8;
  float a3 = 0.f;
  #pragma unroll
  for (int k = 0; k < 8; ++k) {
    float v = fmaf(dx[k], m, xp[k]);
    xo[k] = v;
    if (k == 3) a3 = v;
  }
  alpha2[pix] = a3;
}

// ---------------------------------------------------------------------------
// K7: post_life maxpool + alive gating -> d_out
// ---------------------------------------------------------------------------
__global__ __launch_bounds__(256) void k_life(
    const float* __restrict__ x2, const float* __restrict__ alpha2,
    const float* __restrict__ prelife, float* __restrict__ out) {
  int pix = blockIdx.x * 256 + threadIdx.x;
  int hw = pix & 4095;
  int h = hw >> 6, w = hw & 63;
  const float* ab = alpha2 + (size_t)(pix - hw);
  float mx = -1e30f;
  #pragma unroll
  for (int di = -1; di <= 1; ++di) {
    if ((unsigned)(h + di) > 63u) continue;
    #pragma unroll
    for (int dj = -1; dj <= 1; ++dj) {
      if ((unsigned)(w + dj) > 63u) continue;
      mx = fmaxf(mx, ab[(h + di) * 64 + (w + dj)]);
    }
  }
  float life = (mx > 0.1f && prelife[pix] > 0.5f) ? 1.f : 0.f;
  const float* xp = x2 + (size_t)pix * 8;
  float* op = out + (size_t)pix * 8;
  #pragma unroll
  for (int k = 0; k < 8; ++k) op[k] = xp[k] * life;
}

// ---------------------------------------------------------------------------
extern "C" void kernel_launch(void* const* d_in, const int* in_sizes, int n_in,
                              void* d_out, int out_size, void* d_ws, size_t ws_size,
                              hipStream_t stream) {
  const float* x     = (const float*)d_in[0];
  const float* noise = (const float*)d_in[1];
  const float* Watt  = (const float*)d_in[2];
  const float* b_att = (const float*)d_in[3];
  const float* W1    = (const float*)d_in[4];
  const float* b1    = (const float*)d_in[5];
  const float* Wt    = (const float*)d_in[6];
  const float* bt    = (const float*)d_in[7];
  const float* W2    = (const float*)d_in[8];
  const float* b2    = (const float*)d_in[9];
  const float* W3    = (const float*)d_in[10];
  const float* b3    = (const float*)d_in[11];
  float* out = (float*)d_out;

  float* ws = (float*)d_ws;
  size_t o_y   = 0;                       // y16 [4194304]; later x2+alpha2
  size_t o_h1  = o_y + 4194304;           // h1 [11808768]
  size_t o_y0  = o_h1 + 11808768;         // y0_hwc [98304]
  size_t o_pre = o_y0 + 98304;            // prelife [262144]
  size_t o_att = o_pre + 262144;          // att_acc[648] + ssq[1]
  size_t o_w2t = o_att + 652;             // W2T [6144]
  size_t o_k16 = o_w2t + 6144;            // K16 [19200]
  float* y_chw   = ws + o_y;
  float* h1_chw  = ws + o_h1;
  float* y0_hwc  = ws + o_y0;
  float* prelife = ws + o_pre;
  float* att_acc = ws + o_att;
  float* ssq     = ws + o_att + 648;
  float* W2T     = ws + o_w2t;
  float* K16     = ws + o_k16;
  float* x2      = ws + o_y;              // alias: y dead after k_conv1f
  float* alpha2  = ws + o_y + 2097152;

  k_perceive<<<1025, 256, 0, stream>>>(x, y_chw, y0_hwc, prelife, att_acc, W2, W2T);
  k_att<<<1536, 256, 0, stream>>>(y0_hwc, Watt, att_acc);
  k_ssqfold<<<1049, 256, 0, stream>>>(y_chw, att_acc, b_att, ssq, W1, K16);
  k_conv1f<<<1024, 256, 0, stream>>>(y_chw, K16, b1, ssq, h1_chw);
  k_convTh<<<1024, 256, 0, stream>>>(h1_chw, Wt, bt, W2T, b2, W3, b3, x, noise, x2, alpha2);
  k_life<<<1024, 256, 0, stream>>>(x2, alpha2, prelife, out);
}

// Round 14
// 753.152 us; speedup vs baseline: 1.1691x; 1.1037x over previous
//
#include <hip/hip_runtime.h>

#define NB 64
#define HW 4096           // 64*64

typedef __attribute__((ext_vector_type(8))) short short8;
typedef __attribute__((ext_vector_type(4))) float f32x4;

// round-to-nearest bf16 split helpers
__device__ __forceinline__ unsigned short bf16_rn(float v) {
  unsigned int u = __float_as_uint(v);
  return (unsigned short)((u + 0x7fffu + ((u >> 16) & 1u)) >> 16);
}

// ---------------------------------------------------------------------------
// K1: perceive (fixed stencil) + pre_life + zero accumulators.
// Block 1024: transpose W2 [48,128] -> W2T [128,48] (merged former k_prep).
// ---------------------------------------------------------------------------
__global__ __launch_bounds__(256) void k_perceive(
    const float* __restrict__ x, float* __restrict__ y_chw,
    float* __restrict__ y0_hwc, float* __restrict__ prelife,
    float* __restrict__ att_zero, const float* __restrict__ W2,
    float* __restrict__ W2T) {
  int t = threadIdx.x;
  if (blockIdx.x == 1024) {               // former k_prep
    for (int i = t; i < 6144; i += 256) {
      int o = i / 48;
      int c = i - o * 48;
      W2T[i] = W2[c * 128 + o];
    }
    return;
  }
  if (blockIdx.x == 0) {
    for (int i = t; i < 649; i += 256) att_zero[i] = 0.f;   // att_acc + ssq
  }
  int pix = blockIdx.x * 256 + t;
  int b = pix >> 12;
  int hw = pix & 4095;
  int h = hw >> 6, w = hw & 63;
  const float* xp = x + (size_t)pix * 8;
  bool hm = h > 0, hp = h < 63, wm = w > 0, wp = w < 63;

  float mx = -1e30f;
  #pragma unroll
  for (int di = -1; di <= 1; ++di) {
    if ((unsigned)(h + di) > 63u) continue;
    #pragma unroll
    for (int dj = -1; dj <= 1; ++dj) {
      if ((unsigned)(w + dj) > 63u) continue;
      mx = fmaxf(mx, xp[(di * 64 + dj) * 8 + 3]);
    }
  }
  prelife[pix] = (mx > 0.1f) ? 1.f : 0.f;

  float* yb = y_chw + (size_t)b * 16 * HW + hw;
  bool b0 = (b == 0);
  #pragma unroll
  for (int c = 0; c < 8; ++c) {
    float ctr = xp[c];
    float a00 = (hm && wm) ? xp[(-65) * 8 + c] : 0.f;
    float a02 = (hm && wp) ? xp[(-63) * 8 + c] : 0.f;
    float a20 = (hp && wm) ? xp[(63) * 8 + c] : 0.f;
    float a22 = (hp && wp) ? xp[(65) * 8 + c] : 0.f;
    float d = (a00 + a02 + a20 + a22) * 0.125f;   // dxk == dyk (symmetric)
    yb[(size_t)(c * 2 + 0) * HW] = ctr;
    yb[(size_t)(c * 2 + 1) * HW] = d;
    if (b0) {
      float* y0p = y0_hwc + hw * 24 + c * 3;
      y0p[0] = ctr; y0p[1] = d; y0p[2] = d;
    }
  }
}

// ---------------------------------------------------------------------------
// K2: attention mat-vec, batch 0 only (R12 form: 1536 blocks, 2-row MLP).
// ---------------------------------------------------------------------------
__global__ __launch_bounds__(256) void k_att(
    const float* __restrict__ y0, const float* __restrict__ Watt,
    float* __restrict__ att_acc) {
  int t = threadIdx.x;
  int r0 = blockIdx.x * 64;
  float a0 = 0.f, a1 = 0.f, a2 = 0.f;
  float b0 = 0.f, b1 = 0.f, b2 = 0.f;
  for (int r = 0; r < 64; r += 2) {
    float yv0 = y0[r0 + r];
    float yv1 = y0[r0 + r + 1];
    const float* w0 = Watt + (size_t)(r0 + r) * 648;
    const float* w1 = w0 + 648;
    a0 = fmaf(yv0, w0[t], a0);
    b0 = fmaf(yv1, w1[t], b0);
    a1 = fmaf(yv0, w0[t + 256], a1);
    b1 = fmaf(yv1, w1[t + 256], b1);
    if (t < 136) {
      a2 = fmaf(yv0, w0[t + 512], a2);
      b2 = fmaf(yv1, w1[t + 512], b2);
    }
  }
  atomicAdd(att_acc + t, a0 + b0);
  atomicAdd(att_acc + t + 256, a1 + b1);
  if (t < 136) atomicAdd(att_acc + t + 512, a2 + b2);
}

// ---------------------------------------------------------------------------
// K3: blocks 0..1023: ssq = ||y2||^2 without materializing y2.
//     blocks 1024..1048: fold dw2 o conv1 -> bf16-split K16H/K16L for the
//     MFMA conv1f. Layout [o][k], k = tap*16 + c, 416-padded (400..415 = 0).
// ---------------------------------------------------------------------------
__global__ __launch_bounds__(256) void k_ssqfold(
    const float* __restrict__ y_chw, const float* __restrict__ att_acc,
    const float* __restrict__ b_att, float* __restrict__ ssq,
    const float* __restrict__ W1, unsigned short* __restrict__ K16H,
    unsigned short* __restrict__ K16L) {
  __shared__ float ys[648];
  __shared__ float s[16 * 324];
  int t = threadIdx.x;

  if (blockIdx.x >= 1024) {               // fold path
    for (int i = t; i < 648; i += 256) ys[i] = att_acc[i] + b_att[i];
    __syncthreads();
    int r = blockIdx.x - 1024;            // 0..24 (= tap)
    int ri = r / 5, rj = r - ri * 5;
    #pragma unroll
    for (int k = 0; k < 3; ++k) {
      int idx = t + 256 * k;              // 0..767
      int p = idx / 48;                   // 0..15 (= c plane)
      int o = idx - p * 48;               // 0..47
      int c = p >> 1, tt = p & 1;
      float acc = 0.f;
      for (int ki = 0; ki < 3; ++ki) {
        int qi = ri - ki;
        if ((unsigned)qi > 2u) continue;
        for (int kj = 0; kj < 3; ++kj) {
          int qj = rj - kj;
          if ((unsigned)qj > 2u) continue;
          int k9 = ki * 3 + kj, q9 = qi * 3 + qj;
          const float* wb = W1 + (size_t)(k9 * 72 + 9 * c) * 48 + o;
          const float* yb = ys + q9 * 72 + 9 * c;
          if (tt == 0) {
            #pragma unroll
            for (int m = 0; m < 3; ++m) acc = fmaf(wb[(size_t)m * 48], yb[m], acc);
          } else {
            #pragma unroll
            for (int m = 0; m < 3; ++m) {
              acc = fmaf(wb[(size_t)(3 + m) * 48], yb[3 + m], acc);
              acc = fmaf(wb[(size_t)(6 + m) * 48], yb[6 + m], acc);
            }
          }
        }
      }
      unsigned short hb_ = bf16_rn(acc);
      float fhi = __uint_as_float(((unsigned int)hb_) << 16);
      unsigned short lb_ = bf16_rn(acc - fhi);
      K16H[o * 416 + r * 16 + p] = hb_;
      K16L[o * 416 + r * 16 + p] = lb_;
      if (r == 24) {                      // zero the K-pad 400..415
        K16H[o * 416 + 400 + p] = 0;
        K16L[o * 416 + 400 + p] = 0;
      }
    }
    return;
  }

  for (int i = t; i < 648; i += 256) ys[i] = att_acc[i] + b_att[i];

  int blk = blockIdx.x;
  int b = blk >> 4;
  int tile = blk & 15;
  int i0 = (tile >> 2) * 16;
  int j0 = (tile & 3) * 16;
  const float* yb = y_chw + (size_t)b * 16 * HW;

  for (int idx = t; idx < 16 * 324; idx += 256) {
    int c = idx / 324;
    int pos = idx - c * 324;
    int r = pos / 18, col = pos - r * 18;
    int gr = i0 - 1 + r, gc = j0 - 1 + col;
    bool v = ((unsigned)gr < 64u) && ((unsigned)gc < 64u);
    s[idx] = v ? yb[(size_t)c * HW + gr * 64 + gc] : 0.f;
  }
  __syncthreads();

  int ty = t >> 4, tx = t & 15;
  float local = 0.f;
  for (int c = 0; c < 8; ++c) {
    float tapA[9], tapB[9];
    const float* sa = s + (size_t)(2 * c) * 324 + ty * 18 + tx;
    const float* sb = s + (size_t)(2 * c + 1) * 324 + ty * 18 + tx;
    #pragma unroll
    for (int di = 0; di < 3; ++di)
      #pragma unroll
      for (int dj = 0; dj < 3; ++dj) {
        tapA[di * 3 + dj] = sa[di * 18 + dj];
        tapB[di * 3 + dj] = sb[di * 18 + dj];
      }
    #pragma unroll
    for (int m = 0; m < 3; ++m) {
      float z0 = 0.f, z1 = 0.f, z2 = 0.f;
      #pragma unroll
      for (int k9 = 0; k9 < 9; ++k9) {
        z0 = fmaf(tapA[k9], ys[k9 * 72 + 9 * c + m], z0);
        z1 = fmaf(tapB[k9], ys[k9 * 72 + 9 * c + 3 + m], z1);
        z2 = fmaf(tapB[k9], ys[k9 * 72 + 9 * c + 6 + m], z2);
      }
      local += z0 * z0 + z1 * z1 + z2 * z2;
    }
  }
  #pragma unroll
  for (int off = 32; off; off >>= 1) local += __shfl_down(local, off, 64);
  if ((t & 63) == 0) atomicAdd(ssq, local);
}

// ---------------------------------------------------------------------------
// K4: conv1f as bf16-split MFMA GEMM. Per 16x16-px tile:
//   out[256, 48] = A[256, K=400] x B[400, 48],  K = tap*16 + c (tap-major).
// A staged in LDS as [416 pos][16 c] bf16 hi + lo (26.6KB); an MFMA A-frag
// (8 consecutive k = 8 c-planes at one tap) = one ds_read_b128.
// B = K16H/L [o][416], L2-hot 16B loads; K-pad zeros kill the tail garbage.
// 3-split products hi*hi + hi*lo + lo*hi ~ fp32 precision.
// Wave w owns m-tiles 4w..4w+3 (pixel rows), all 3 n-tiles; 468 MFMA/wave.
// D layout: col(o)=lane&15, row(px)=(lane>>4)*4+reg (guide-verified).
// ---------------------------------------------------------------------------
__global__ __launch_bounds__(256, 4) void k_conv1f(
    const float* __restrict__ y_chw, const unsigned short* __restrict__ K16H,
    const unsigned short* __restrict__ K16L, const float* __restrict__ b1,
    const float* __restrict__ ssqp, float* __restrict__ h1) {
  __shared__ short sh[2 * 6656];          // [hi|lo][pos*16+c], pos 0..415
  int t = threadIdx.x;
  int w = t >> 6, lane = t & 63;
  int blk = blockIdx.x;
  int b = blk >> 4;
  int tile = blk & 15;
  int i0 = (tile >> 2) * 16; if (i0 > 46) i0 = 46;
  int j0 = (tile & 3) * 16;  if (j0 > 46) j0 = 46;

  const float* yb = y_chw + (size_t)b * 16 * HW;
  // stage + bf16-split: LDS[pos][c] from y[c][i0-1+pos/20][j0-1+pos%20]
  for (int idx = t; idx < 16 * 400; idx += 256) {
    int c = idx / 400;
    int pos = idx - c * 400;
    int r = pos / 20, col = pos - r * 20;
    int gr = i0 - 1 + r, gc = j0 - 1 + col;
    bool v = ((unsigned)gr < 64u) && ((unsigned)gc < 64u);
    float val = v ? yb[(size_t)c * HW + gr * 64 + gc] : 0.f;
    unsigned short hb_ = bf16_rn(val);
    float fhi = __uint_as_float(((unsigned int)hb_) << 16);
    unsigned short lb_ = bf16_rn(val - fhi);
    sh[pos * 16 + c] = (short)hb_;
    sh[6656 + pos * 16 + c] = (short)lb_;
  }
  if (t < 256) {                          // zero pad pos 400..415 (16x16)
    sh[6400 + t] = 0;
    sh[6656 + 6400 + t] = 0;
  }
  __syncthreads();

  f32x4 acc[4][3];
  #pragma unroll
  for (int m = 0; m < 4; ++m)
    #pragma unroll
    for (int n = 0; n < 3; ++n) acc[m][n] = (f32x4){0.f, 0.f, 0.f, 0.f};

  int lanecol = lane & 15;
  int half = (lane >> 4) >> 1;            // 0,0,1,1 across lane>>4
  int c0 = ((lane >> 4) & 1) * 8;         // 0,8,0,8

  for (int ks = 0; ks < 13; ++ks) {
    // B fragments (hi+lo) for 3 n-tiles: 16B L2-hot loads
    short8 bh[3], bl[3];
    #pragma unroll
    for (int n = 0; n < 3; ++n) {
      int o = n * 16 + lanecol;
      size_t boff = (size_t)o * 416 + ks * 32 + (lane >> 4) * 8;
      bh[n] = *(const short8*)(K16H + boff);
      bl[n] = *(const short8*)(K16L + boff);
    }
    int tap = 2 * ks + half;              // 0..25 (25 = pad, B=0 there)
    int ri = tap / 5, rj = tap - ri * 5;
    int aoff = (ri * 20 + rj + lanecol) * 16 + c0;
    #pragma unroll
    for (int m = 0; m < 4; ++m) {
      int mt = (w << 2) + m;              // pixel row in tile
      int ao = aoff + mt * 320;           // (mt+ri)*20*16 folded in
      short8 ah = *(const short8*)(sh + ao);
      short8 al = *(const short8*)(sh + 6656 + ao);
      #pragma unroll
      for (int n = 0; n < 3; ++n) {
        acc[m][n] = __builtin_amdgcn_mfma_f32_16x16x32_bf16(ah, bh[n], acc[m][n], 0, 0, 0);
        acc[m][n] = __builtin_amdgcn_mfma_f32_16x16x32_bf16(ah, bl[n], acc[m][n], 0, 0, 0);
        acc[m][n] = __builtin_amdgcn_mfma_f32_16x16x32_bf16(al, bh[n], acc[m][n], 0, 0, 0);
      }
    }
  }

  float inv = rsqrtf(fmaxf(ssqp[0], 1e-12f));
  int rg = lane >> 4;                     // D row group: px = rg*4 + reg
  #pragma unroll
  for (int n = 0; n < 3; ++n) {
    int o = n * 16 + lanecol;
    float bo = b1[o];
    #pragma unroll
    for (int m = 0; m < 4; ++m) {
      int mt = (w << 2) + m;
      float* hp = h1 + ((size_t)b * 48 + o) * 3844 + (i0 + mt) * 62 + j0 + rg * 4;
      #pragma unroll
      for (int r = 0; r < 4; ++r) hp[r] = fmaf(acc[m][n][r], inv, bo);
    }
  }
}

// ---------------------------------------------------------------------------
// K5: fused convT (3x3 pad-2 correlation 48->48) + head (48->128 relu ->8)
// + masked residual. Exact R8/R12-winner form (CONTROL: ~219us, VGPR 44).
// ---------------------------------------------------------------------------
__global__ __launch_bounds__(256, 4) void k_convTh(
    const float* __restrict__ h1, const float* __restrict__ Wt,
    const float* __restrict__ bt, const float* __restrict__ W2T,
    const float* __restrict__ b2, const float* __restrict__ W3,
    const float* __restrict__ b3, const float* __restrict__ x,
    const float* __restrict__ noise, float* __restrict__ x2,
    float* __restrict__ alpha2) {
  __shared__ float s[24 * 324];           // staging 7776 fl; exchange uses 6144
  int t = threadIdx.x;
  int og = __builtin_amdgcn_readfirstlane(t >> 7);      // wave-uniform 0/1
  int sub = t & 127;
  int ty = sub >> 4, tx = sub & 15;
  int blk = blockIdx.x;
  int b = blk >> 4;
  int tile = blk & 15;
  int i0 = (tile >> 2) * 16;
  int j0 = (tile & 3) * 16;

  float acc0[24], acc1[24];
  #pragma unroll
  for (int o = 0; o < 24; ++o) { acc0[o] = 0.f; acc1[o] = 0.f; }
  const float* hb = h1 + (size_t)b * 48 * 3844;

  for (int c0 = 0; c0 < 48; c0 += 24) {
    __syncthreads();
    for (int idx = t; idx < 24 * 324; idx += 256) {
      int c = idx / 324;
      int pos = idx - c * 324;
      int r = pos / 18, col = pos - r * 18;
      int gr = i0 - 2 + r, gc = j0 - 2 + col;
      bool v = ((unsigned)gr < 62u) && ((unsigned)gc < 62u);
      s[idx] = v ? hb[(size_t)(c0 + c) * 3844 + gr * 62 + gc] : 0.f;
    }
    __syncthreads();
    for (int c = 0; c < 24; ++c) {
      const float* sc = s + c * 324 + ty * 18 + tx;
      float tap0[9], tap1[9];
      #pragma unroll
      for (int di = 0; di < 3; ++di)
        #pragma unroll
        for (int dj = 0; dj < 3; ++dj) {
          tap0[di * 3 + dj] = sc[di * 18 + dj];
          tap1[di * 3 + dj] = sc[(di + 8) * 18 + dj];
        }
      #pragma unroll
      for (int k9 = 0; k9 < 9; ++k9) {
        const float* w = Wt + (size_t)(k9 * 48 + c0 + c) * 48 + og * 24;  // SGPR
        float tv0 = tap0[k9], tv1 = tap1[k9];
        #pragma unroll
        for (int o = 0; o < 24; ++o) {
          acc0[o] = fmaf(tv0, w[o], acc0[o]);
          acc1[o] = fmaf(tv1, w[o], acc1[o]);
        }
      }
    }
  }

  // two-phase h2-tile exchange
  float hr[48];
  #pragma unroll
  for (int ph = 0; ph < 2; ++ph) {
    __syncthreads();
    if (og == ph) {
      #pragma unroll
      for (int o = 0; o < 24; ++o) {
        float bo = bt[ph * 24 + o];
        s[o * 256 + ty * 16 + tx] = acc0[o] + bo;
        s[o * 256 + (ty + 8) * 16 + tx] = acc1[o] + bo;
      }
    }
    __syncthreads();
    #pragma unroll
    for (int c = 0; c < 24; ++c) hr[ph * 24 + c] = s[c * 256 + t];
  }

  // head: one pixel per thread; unroll 4
  int pty = t >> 4, ptx = t & 15;
  int pix = b * 4096 + (i0 + pty) * 64 + (j0 + ptx);
  float dx[8];
  #pragma unroll
  for (int k = 0; k < 8; ++k) dx[k] = b3[k];
  #pragma unroll 4
  for (int o = 0; o < 128; ++o) {
    float v = b2[o];
    const float* w2 = W2T + o * 48;
    #pragma unroll
    for (int c = 0; c < 48; ++c) v = fmaf(hr[c], w2[c], v);
    v = fmaxf(v, 0.f);
    const float* w3 = W3 + o * 8;
    #pragma unroll
    for (int k = 0; k < 8; ++k) dx[k] = fmaf(v, w3[k], dx[k]);
  }
  float m = (noise[pix] <= 0.5f) ? 1.f : 0.f;
  const float* xp = x + (size_t)pix * 8;
  float* xo = x2 + (size_t)pix * 8;
  float a3 = 0.f;
  #pragma unroll
  for (int k = 0; k < 8; ++k) {
    float v = fmaf(dx[k], m, xp[k]);
    xo[k] = v;
    if (k == 3) a3 = v;
  }
  alpha2[pix] = a3;
}

// ---------------------------------------------------------------------------
// K7: post_life maxpool + alive gating -> d_out
// ---------------------------------------------------------------------------
__global__ __launch_bounds__(256) void k_life(
    const float* __restrict__ x2, const float* __restrict__ alpha2,
    const float* __restrict__ prelife, float* __restrict__ out) {
  int pix = blockIdx.x * 256 + threadIdx.x;
  int hw = pix & 4095;
  int h = hw >> 6, w = hw & 63;
  const float* ab = alpha2 + (size_t)(pix - hw);
  float mx = -1e30f;
  #pragma unroll
  for (int di = -1; di <= 1; ++di) {
    if ((unsigned)(h + di) > 63u) continue;
    #pragma unroll
    for (int dj = -1; dj <= 1; ++dj) {
      if ((unsigned)(w + dj) > 63u) continue;
      mx = fmaxf(mx, ab[(h + di) * 64 + (w + dj)]);
    }
  }
  float life = (mx > 0.1f && prelife[pix] > 0.5f) ? 1.f : 0.f;
  const float* xp = x2 + (size_t)pix * 8;
  float* op = out + (size_t)pix * 8;
  #pragma unroll
  for (int k = 0; k < 8; ++k) op[k] = xp[k] * life;
}

// ---------------------------------------------------------------------------
extern "C" void kernel_launch(void* const* d_in, const int* in_sizes, int n_in,
                              void* d_out, int out_size, void* d_ws, size_t ws_size,
                              hipStream_t stream) {
  const float* x     = (const float*)d_in[0];
  const float* noise = (const float*)d_in[1];
  const float* Watt  = (const float*)d_in[2];
  const float* b_att = (const float*)d_in[3];
  const float* W1    = (const float*)d_in[4];
  const float* b1    = (const float*)d_in[5];
  const float* Wt    = (const float*)d_in[6];
  const float* bt    = (const float*)d_in[7];
  const float* W2    = (const float*)d_in[8];
  const float* b2    = (const float*)d_in[9];
  const float* W3    = (const float*)d_in[10];
  const float* b3    = (const float*)d_in[11];
  float* out = (float*)d_out;

  float* ws = (float*)d_ws;
  size_t o_y   = 0;                       // y16 [4194304]; later x2+alpha2
  size_t o_h1  = o_y + 4194304;           // h1 [11808768]
  size_t o_y0  = o_h1 + 11808768;         // y0_hwc [98304]
  size_t o_pre = o_y0 + 98304;            // prelife [262144]
  size_t o_att = o_pre + 262144;          // att_acc[648] + ssq[1]
  size_t o_w2t = o_att + 652;             // W2T [6144]
  size_t o_kh  = o_w2t + 6144;            // K16H [48*416 u16 = 9984 fl]
  size_t o_kl  = o_kh + 9984;             // K16L [9984 fl]
  float* y_chw   = ws + o_y;
  float* h1_chw  = ws + o_h1;
  float* y0_hwc  = ws + o_y0;
  float* prelife = ws + o_pre;
  float* att_acc = ws + o_att;
  float* ssq     = ws + o_att + 648;
  float* W2T     = ws + o_w2t;
  unsigned short* K16H = (unsigned short*)(ws + o_kh);
  unsigned short* K16L = (unsigned short*)(ws + o_kl);
  float* x2      = ws + o_y;              // alias: y dead after k_conv1f
  float* alpha2  = ws + o_y + 2097152;

  k_perceive<<<1025, 256, 0, stream>>>(x, y_chw, y0_hwc, prelife, att_acc, W2, W2T);
  k_att<<<1536, 256, 0, stream>>>(y0_hwc, Watt, att_acc);
  k_ssqfold<<<1049, 256, 0, stream>>>(y_chw, att_acc, b_att, ssq, W1, K16H, K16L);
  k_conv1f<<<1024, 256, 0, stream>>>(y_chw, K16H, K16L, b1, ssq, h1_chw);
  k_convTh<<<1024, 256, 0, stream>>>(h1_chw, Wt, bt, W2T, b2, W3, b3, x, noise, x2, alpha2);
  k_life<<<1024, 256, 0, stream>>>(x2, alpha2, prelife, out);
}